// Round 1
// baseline (25266.685 us; speedup 1.0000x reference)
//
#include <hip/hip_runtime.h>
#include <cstddef>

// ---------------- T5-Base config (fixed) ----------------
constexpr int Bz  = 4;
constexpr int Sq  = 512;     // SE == SD == 512
constexpr int Dm  = 768;
constexpr int Hh  = 12;
constexpr int HDm = 64;
constexpr int Mf  = 3072;
constexpr int Ll  = 6;
constexpr int Vv  = 32128;
constexpr int NT  = Bz * Sq;          // 2048 token rows
constexpr int NBK = 32;               // num relpos buckets
#define NEG_INF_F (-1e10f)

// ---------------- relative-position bucket LUT ----------------
// bucket depends only on delta = j - i  (delta in [-511, 511])
__global__ void build_lut_kernel(int* __restrict__ lut_enc, int* __restrict__ lut_dec) {
    int t = blockIdx.x * blockDim.x + threadIdx.x;
    if (t >= 1023) return;
    int delta = t - 511;          // j - i
    // encoder: bidirectional, num_buckets 16 after halving, max_exact 8
    {
        int n = -delta;           // i - j
        int ret = 0;
        if (n < 0) { ret = 16; n = -n; }
        int b;
        if (n < 8) b = ret + n;
        else {
            int v = 8 + (int)(logf((float)n / 8.0f) / logf(16.0f) * 8.0f);
            if (v > 15) v = 15;
            b = ret + v;
        }
        lut_enc[t] = b;
    }
    // decoder self: unidirectional, num_buckets 32, max_exact 16
    {
        int n = delta < 0 ? -delta : 0;   // max(i - j, 0)
        int b;
        if (n < 16) b = n;
        else {
            b = 16 + (int)(logf((float)n / 16.0f) / logf(8.0f) * 16.0f);
            if (b > 31) b = 31;
        }
        lut_dec[t] = b;
    }
}

// ---------------- embedding gather ----------------
__global__ void embed_kernel(const float* __restrict__ emb, const int* __restrict__ tok,
                             float* __restrict__ out) {
    int r = blockIdx.x;                    // token row 0..NT-1
    int t = tok[r];
    const float* e = emb + (size_t)t * Dm;
    float* o = out + (size_t)r * Dm;
    for (int d = threadIdx.x; d < Dm; d += 256) o[d] = e[d];
}

// ---------------- RMS norm (row = 768) ----------------
__global__ __launch_bounds__(256) void rmsnorm_kernel(const float* __restrict__ in,
                                                      const float* __restrict__ scale,
                                                      float* __restrict__ out) {
    __shared__ float red[8];
    const float* row = in + (size_t)blockIdx.x * Dm;
    float* orow      = out + (size_t)blockIdx.x * Dm;
    int tid = threadIdx.x;
    float a = row[tid], b = row[tid + 256], c = row[tid + 512];
    float s = a * a + b * b + c * c;
    for (int o = 32; o; o >>= 1) s += __shfl_down(s, o, 64);
    int wid = tid >> 6, lane = tid & 63;
    if (lane == 0) red[wid] = s;
    __syncthreads();
    if (tid == 0) red[4] = red[0] + red[1] + red[2] + red[3];
    __syncthreads();
    float r = 1.0f / sqrtf(red[4] * (1.0f / (float)Dm) + 1e-6f);
    orow[tid]       = a * r * scale[tid];
    orow[tid + 256] = b * r * scale[tid + 256];
    orow[tid + 512] = c * r * scale[tid + 512];
}

// ---------------- generic fp32 GEMM: C = A[MxK] @ B[KxN] (+C) (ReLU) ----------------
// M % 128 == 0, N % 128 == 0, K % 16 == 0 (holds for all shapes used here)
template <int ACC, int RELU>
__global__ __launch_bounds__(256) void gemm_kernel(const float* __restrict__ A,
                                                   const float* __restrict__ B,
                                                   float* __restrict__ C,
                                                   int M, int N, int K) {
    __shared__ float As[16][128];   // [k][m]
    __shared__ float Bs[16][128];   // [k][n]
    const int tid = threadIdx.x;
    const int bm = blockIdx.y * 128;
    const int bn = blockIdx.x * 128;
    const int tx = tid & 15, ty = tid >> 4;

    float acc[8][8];
#pragma unroll
    for (int i = 0; i < 8; ++i)
#pragma unroll
        for (int j = 0; j < 8; ++j) acc[i][j] = 0.0f;

    const int nk = K >> 4;
    for (int kt = 0; kt < nk; ++kt) {
        const int k0 = kt << 4;
#pragma unroll
        for (int i = 0; i < 2; ++i) {
            int l  = i * 256 + tid;
            int r  = l >> 2, c4 = l & 3;                   // A: 128 rows x 4 float4
            const float4 av = *(const float4*)(A + (size_t)(bm + r) * K + k0 + c4 * 4);
            As[c4 * 4 + 0][r] = av.x;
            As[c4 * 4 + 1][r] = av.y;
            As[c4 * 4 + 2][r] = av.z;
            As[c4 * 4 + 3][r] = av.w;
            int kk = l >> 5, c = l & 31;                   // B: 16 rows x 32 float4
            const float4 bv = *(const float4*)(B + (size_t)(k0 + kk) * N + bn + c * 4);
            *(float4*)(&Bs[kk][c * 4]) = bv;
        }
        __syncthreads();
#pragma unroll
        for (int kk = 0; kk < 16; ++kk) {
            float a[8], b[8];
#pragma unroll
            for (int i = 0; i < 8; ++i) a[i] = As[kk][ty * 8 + i];
#pragma unroll
            for (int j = 0; j < 8; ++j) b[j] = Bs[kk][tx * 8 + j];
#pragma unroll
            for (int i = 0; i < 8; ++i)
#pragma unroll
                for (int j = 0; j < 8; ++j) acc[i][j] += a[i] * b[j];
        }
        __syncthreads();
    }
#pragma unroll
    for (int i = 0; i < 8; ++i) {
        int row = bm + ty * 8 + i;
        float* cp = C + (size_t)row * N + bn + tx * 8;
#pragma unroll
        for (int j = 0; j < 8; ++j) {
            float v = acc[i][j];
            if (ACC) v += cp[j];
            if (RELU) v = fmaxf(v, 0.0f);
            cp[j] = v;
        }
    }
}

static inline void launch_gemm(hipStream_t st, const float* A, const float* B, float* C,
                               int M, int N, int K, bool acc, bool relu) {
    dim3 g(N / 128, M / 128), blk(256);
    if (acc)       gemm_kernel<1, 0><<<g, blk, 0, st>>>(A, B, C, M, N, K);
    else if (relu) gemm_kernel<0, 1><<<g, blk, 0, st>>>(A, B, C, M, N, K);
    else           gemm_kernel<0, 0><<<g, blk, 0, st>>>(A, B, C, M, N, K);
}

// ---------------- attention scores: sc[b,h,i,j] = q.k + bias, masked ----------------
// q,k: [B,S,H,HD]; sc: [B,H,S,S]; rel: [H,32] or null; lut: delta->bucket or null
__global__ __launch_bounds__(256) void attn_scores_kernel(const float* __restrict__ q,
                                                          const float* __restrict__ k,
                                                          float* __restrict__ sc,
                                                          const float* __restrict__ rel,
                                                          const int* __restrict__ lut,
                                                          const int* __restrict__ qtok,
                                                          const int* __restrict__ ktok,
                                                          int causal) {
    __shared__ float qs[32][65];
    __shared__ float ks[32][65];
    const int j0 = blockIdx.x * 32, i0 = blockIdx.y * 32;
    const int bh = blockIdx.z;
    const int b = bh / Hh, hh = bh % Hh;
    const int tid = threadIdx.x;
    const int tx = tid & 31, ty = tid >> 5;

    // fully-masked causal tile: just write NEG_INF (softmax reads whole row)
    if (causal && j0 > i0 + 31) {
        int j = j0 + tx;
#pragma unroll
        for (int ii = 0; ii < 4; ++ii) {
            int i = i0 + ty * 4 + ii;
            sc[(((size_t)(b * Hh + hh)) * Sq + i) * Sq + j] = NEG_INF_F;
        }
        return;
    }

#pragma unroll
    for (int it = 0; it < 8; ++it) {
        int l = it * 256 + tid;
        int r = l >> 6, c = l & 63;
        qs[r][c] = q[((size_t)(b * Sq + i0 + r) * Hh + hh) * HDm + c];
        ks[r][c] = k[((size_t)(b * Sq + j0 + r) * Hh + hh) * HDm + c];
    }
    __syncthreads();

    float acc[4] = {0.f, 0.f, 0.f, 0.f};
    for (int hd = 0; hd < HDm; ++hd) {
        float kv = ks[tx][hd];
#pragma unroll
        for (int ii = 0; ii < 4; ++ii) acc[ii] += qs[ty * 4 + ii][hd] * kv;
    }

    int j = j0 + tx;
    int kvalid = ktok[b * Sq + j] > 0;
#pragma unroll
    for (int ii = 0; ii < 4; ++ii) {
        int i = i0 + ty * 4 + ii;
        float v = acc[ii];
        if (rel) v += rel[hh * NBK + lut[j - i + 511]];
        bool ok = kvalid && (qtok[b * Sq + i] > 0);
        if (causal && j > i) ok = false;
        sc[(((size_t)(b * Hh + hh)) * Sq + i) * Sq + j] = ok ? v : NEG_INF_F;
    }
}

// ---------------- softmax over last dim (row length 512), in place ----------------
__global__ __launch_bounds__(256) void softmax_kernel(float* __restrict__ s) {
    __shared__ float red[8];
    float* row = s + (size_t)blockIdx.x * Sq;
    int tid = threadIdx.x;
    float v0 = row[tid], v1 = row[tid + 256];
    float m = fmaxf(v0, v1);
    for (int o = 32; o; o >>= 1) m = fmaxf(m, __shfl_down(m, o, 64));
    int wid = tid >> 6, lane = tid & 63;
    if (lane == 0) red[wid] = m;
    __syncthreads();
    if (tid == 0) red[4] = fmaxf(fmaxf(red[0], red[1]), fmaxf(red[2], red[3]));
    __syncthreads();
    m = red[4];
    float e0 = __expf(v0 - m), e1 = __expf(v1 - m);
    float sum = e0 + e1;
    for (int o = 32; o; o >>= 1) sum += __shfl_down(sum, o, 64);
    if (lane == 0) red[wid] = sum;
    __syncthreads();
    if (tid == 0) red[5] = red[0] + red[1] + red[2] + red[3];
    __syncthreads();
    float inv = 1.0f / red[5];
    row[tid] = e0 * inv;
    row[tid + 256] = e1 * inv;
}

// ---------------- P @ V: ctx[b,i,h,hd] = sum_j p[b,h,i,j] v[b,j,h,hd] ----------------
__global__ __launch_bounds__(256) void attn_pv_kernel(const float* __restrict__ p,
                                                      const float* __restrict__ v,
                                                      float* __restrict__ ctx) {
    __shared__ float ps[32][33];
    __shared__ float vs[32][64];
    const int i0 = blockIdx.x * 32;
    const int bh = blockIdx.y;
    const int b = bh / Hh, hh = bh % Hh;
    const int tid = threadIdx.x;
    const int hd = tid & 63, iq = tid >> 6;   // iq 0..3
    float acc[8];
#pragma unroll
    for (int ii = 0; ii < 8; ++ii) acc[ii] = 0.0f;

    for (int jt = 0; jt < 16; ++jt) {
        int j0 = jt * 32;
#pragma unroll
        for (int it = 0; it < 4; ++it) {
            int l = it * 256 + tid;
            int r = l >> 5, c = l & 31;
            ps[r][c] = p[(((size_t)(b * Hh + hh)) * Sq + i0 + r) * Sq + j0 + c];
        }
#pragma unroll
        for (int it = 0; it < 8; ++it) {
            int l = it * 256 + tid;
            int r = l >> 6, c = l & 63;
            vs[r][c] = v[((size_t)(b * Sq + j0 + r) * Hh + hh) * HDm + c];
        }
        __syncthreads();
#pragma unroll
        for (int jj = 0; jj < 32; ++jj) {
            float vv = vs[jj][hd];
#pragma unroll
            for (int ii = 0; ii < 8; ++ii) acc[ii] += ps[iq + 4 * ii][jj] * vv;
        }
        __syncthreads();
    }
#pragma unroll
    for (int ii = 0; ii < 8; ++ii) {
        int i = i0 + iq + 4 * ii;
        ctx[((size_t)(b * Sq + i) * Hh + hh) * HDm + hd] = acc[ii];
    }
}

// ---------------- orchestration ----------------
extern "C" void kernel_launch(void* const* d_in, const int* in_sizes, int n_in,
                              void* d_out, int out_size, void* d_ws, size_t ws_size,
                              hipStream_t stream) {
    (void)in_sizes; (void)n_in; (void)out_size; (void)ws_size;
    const float* emb      = (const float*)d_in[0];
    const float* rel_enc  = (const float*)d_in[1];
    const float* rel_dec  = (const float*)d_in[2];
    const float* enc_ln1  = (const float*)d_in[3];
    const float* enc_wq   = (const float*)d_in[4];
    const float* enc_wk   = (const float*)d_in[5];
    const float* enc_wv   = (const float*)d_in[6];
    const float* enc_wo   = (const float*)d_in[7];
    const float* enc_ln2  = (const float*)d_in[8];
    const float* enc_wi   = (const float*)d_in[9];
    const float* enc_wmo  = (const float*)d_in[10];
    const float* enc_nrm  = (const float*)d_in[11];
    const float* dec_ln1  = (const float*)d_in[12];
    const float* dec_sq   = (const float*)d_in[13];
    const float* dec_sk   = (const float*)d_in[14];
    const float* dec_sv   = (const float*)d_in[15];
    const float* dec_so   = (const float*)d_in[16];
    const float* dec_ln2  = (const float*)d_in[17];
    const float* dec_cq   = (const float*)d_in[18];
    const float* dec_ck   = (const float*)d_in[19];
    const float* dec_cv   = (const float*)d_in[20];
    const float* dec_co   = (const float*)d_in[21];
    const float* dec_ln3  = (const float*)d_in[22];
    const float* dec_wi   = (const float*)d_in[23];
    const float* dec_wmo  = (const float*)d_in[24];
    const float* dec_nrm  = (const float*)d_in[25];
    const float* logits_w = (const float*)d_in[26];
    const int* enc_tok    = (const int*)d_in[27];
    const int* dec_in_tok = (const int*)d_in[28];
    const int* dec_tgt    = (const int*)d_in[29];
    float* out = (float*)d_out;

    // workspace layout (floats)
    const size_t BSD = (size_t)NT * Dm;                 // 1,572,864
    float* ws  = (float*)d_ws;
    float* x   = ws;                // current activations [NT, D]
    float* h   = x + BSD;           // normed input; also reused as ctx (safe: h dead by PV time)
    float* q   = h + BSD;
    float* k   = q + BSD;
    float* v   = k + BSD;
    float* enc = v + BSD;           // encoder output (encoded)
    float* big = enc + BSD;         // scores [B*H*S*S]=12.58M floats; shared with MLP hidden [NT*M]=6.29M
    int*   lut_e = (int*)(big + (size_t)Bz * Hh * Sq * Sq);
    int*   lut_d = lut_e + 1024;

    const size_t Wqkv = (size_t)Dm * Hh * HDm;   // 589824 per layer
    const size_t Wmlp = (size_t)Dm * Mf;         // 2359296 per layer

    dim3 blk(256);
    build_lut_kernel<<<dim3(4), blk, 0, stream>>>(lut_e, lut_d);

    // ================= Encoder =================
    embed_kernel<<<dim3(NT), blk, 0, stream>>>(emb, enc_tok, x);
    for (int l = 0; l < Ll; ++l) {
        rmsnorm_kernel<<<dim3(NT), blk, 0, stream>>>(x, enc_ln1 + (size_t)l * Dm, h);
        launch_gemm(stream, h, enc_wq + l * Wqkv, q, NT, Dm, Dm, false, false);
        launch_gemm(stream, h, enc_wk + l * Wqkv, k, NT, Dm, Dm, false, false);
        launch_gemm(stream, h, enc_wv + l * Wqkv, v, NT, Dm, Dm, false, false);
        attn_scores_kernel<<<dim3(16, 16, Bz * Hh), blk, 0, stream>>>(
            q, k, big, rel_enc, lut_e, enc_tok, enc_tok, 0);
        softmax_kernel<<<dim3(Bz * Hh * Sq), blk, 0, stream>>>(big);
        attn_pv_kernel<<<dim3(16, Bz * Hh), blk, 0, stream>>>(big, v, h);  // ctx -> h
        launch_gemm(stream, h, enc_wo + l * Wqkv, x, NT, Dm, Dm, true, false);  // x += ctx@wo
        rmsnorm_kernel<<<dim3(NT), blk, 0, stream>>>(x, enc_ln2 + (size_t)l * Dm, h);
        launch_gemm(stream, h, enc_wi + l * Wmlp, big, NT, Mf, Dm, false, true);   // relu(h@wi)
        launch_gemm(stream, big, enc_wmo + l * Wmlp, x, NT, Dm, Mf, true, false);  // x += hid@wmo
    }
    rmsnorm_kernel<<<dim3(NT), blk, 0, stream>>>(x, enc_nrm, enc);

    // ================= Decoder =================
    embed_kernel<<<dim3(NT), blk, 0, stream>>>(emb, dec_in_tok, x);
    for (int l = 0; l < Ll; ++l) {
        // self-attention (causal, dec relpos bias, tgt-valid mask both sides)
        rmsnorm_kernel<<<dim3(NT), blk, 0, stream>>>(x, dec_ln1 + (size_t)l * Dm, h);
        launch_gemm(stream, h, dec_sq + l * Wqkv, q, NT, Dm, Dm, false, false);
        launch_gemm(stream, h, dec_sk + l * Wqkv, k, NT, Dm, Dm, false, false);
        launch_gemm(stream, h, dec_sv + l * Wqkv, v, NT, Dm, Dm, false, false);
        attn_scores_kernel<<<dim3(16, 16, Bz * Hh), blk, 0, stream>>>(
            q, k, big, rel_dec, lut_d, dec_tgt, dec_tgt, 1);
        softmax_kernel<<<dim3(Bz * Hh * Sq), blk, 0, stream>>>(big);
        attn_pv_kernel<<<dim3(16, Bz * Hh), blk, 0, stream>>>(big, v, h);
        launch_gemm(stream, h, dec_so + l * Wqkv, x, NT, Dm, Dm, true, false);
        // cross-attention (no bias, q from y, k/v from encoded, tgt x enc mask)
        rmsnorm_kernel<<<dim3(NT), blk, 0, stream>>>(x, dec_ln2 + (size_t)l * Dm, h);
        launch_gemm(stream, h,   dec_cq + l * Wqkv, q, NT, Dm, Dm, false, false);
        launch_gemm(stream, enc, dec_ck + l * Wqkv, k, NT, Dm, Dm, false, false);
        launch_gemm(stream, enc, dec_cv + l * Wqkv, v, NT, Dm, Dm, false, false);
        attn_scores_kernel<<<dim3(16, 16, Bz * Hh), blk, 0, stream>>>(
            q, k, big, nullptr, nullptr, dec_tgt, enc_tok, 0);
        softmax_kernel<<<dim3(Bz * Hh * Sq), blk, 0, stream>>>(big);
        attn_pv_kernel<<<dim3(16, Bz * Hh), blk, 0, stream>>>(big, v, h);
        launch_gemm(stream, h, dec_co + l * Wqkv, x, NT, Dm, Dm, true, false);
        // MLP
        rmsnorm_kernel<<<dim3(NT), blk, 0, stream>>>(x, dec_ln3 + (size_t)l * Dm, h);
        launch_gemm(stream, h, dec_wi + l * Wmlp, big, NT, Mf, Dm, false, true);
        launch_gemm(stream, big, dec_wmo + l * Wmlp, x, NT, Dm, Mf, true, false);
    }
    rmsnorm_kernel<<<dim3(NT), blk, 0, stream>>>(x, dec_nrm, h);

    // ================= logits =================
    launch_gemm(stream, h, logits_w, out, NT, Vv, Dm, false, false);
}